// Round 8
// baseline (229.826 us; speedup 1.0000x reference)
//
#include <hip/hip_runtime.h>
#include <hip/hip_bf16.h>

// ---------------------------------------------------------------------------
// SCSAttention on MI355X, round 8 = round 7 + fused attention (logits+softmax+PV
// in one kernel) + fused r_g1/wtrans. 13 launches.
//   - 2-phase double-buffered global_load_lds K-loop in all GEMMs.
//   - G1 mixed: Q/K blocks 3-pass split, V blocks 1-pass (SPL=2).
//   - kc constants fused into the A3 split-K reduce.
// Sensitive path (Q/K/logits) = bf16x2 hi/lo 3-pass.
// ---------------------------------------------------------------------------

typedef __attribute__((ext_vector_type(8))) short short8;
typedef __attribute__((ext_vector_type(4))) float f32x4;

#define TOKENS 1568

__device__ __forceinline__ ushort f2bf(float f) {
    uint32_t u = __float_as_uint(f);
    u += 0x7fffu + ((u >> 16) & 1u);   // RNE
    return (ushort)(u >> 16);
}
__device__ __forceinline__ float bf2f(ushort h) { return __uint_as_float(((uint32_t)h) << 16); }
__device__ __forceinline__ void split2(float v, ushort& h, ushort& l) {
    h = f2bf(v); l = f2bf(v - bf2f(h));
}

__device__ __forceinline__ void gl16(const void* g, void* l) {
    __builtin_amdgcn_global_load_lds(
        (const __attribute__((address_space(1))) unsigned int*)g,
        (__attribute__((address_space(3))) unsigned int*)l, 16, 0, 0);
}

#define EPI_PART  0
#define EPI_BF16  1
#define EPI_SPLIT 2
#define EPI_FINAL 3

// C[m][n] = sum_k A[m][k]*W[n][k]; tile 64(M)x128(N), BK=32, 4 waves (2x2),
// wave = 32x64 = 2x4 16x16 frags. SPL: 0 plain, 1 split 3-pass, 2 split iff blockIdx.x<2.
// Double-buffered LDS: STAGE(next) issued before MFMA(cur), one barrier per K-step.
template<int EPI, int SPL>
__global__ __launch_bounds__(256)
void gmm(const ushort* __restrict__ Ah, const ushort* __restrict__ Al, int lda, long sA,
         const ushort* __restrict__ Wh, const ushort* __restrict__ Wl, int ldw, long sW,
         const float* __restrict__ bias, int sB,
         int nkc, int Kc,
         float* __restrict__ fO, ushort* __restrict__ bO, ushort* __restrict__ bO2,
         int ldc, long sC, int M, int N,
         const float* __restrict__ ex, const float* __restrict__ gamma,
         float* __restrict__ fout)
{
    constexpr bool HASL = (SPL >= 1);
    __shared__ __align__(16) ushort sA_h[2][64 * 32];
    __shared__ __align__(16) ushort sW_h[2][128 * 32];
    __shared__ __align__(16) ushort sA_l[HASL ? 2 : 1][HASL ? 64 * 32 : 8];
    __shared__ __align__(16) ushort sW_l[HASL ? 2 : 1][HASL ? 128 * 32 : 8];

    const int tid = threadIdx.x;
    const int bz = blockIdx.z / nkc;
    const int kc = blockIdx.z % nkc;
    const int row0 = blockIdx.y * 64, col0 = blockIdx.x * 128;
    const bool sp = (SPL == 1) || (SPL == 2 && blockIdx.x < 2);

    // ---- staging addresses (lane supplies one 16B chunk per call) ----
    const int srow = tid >> 2;                       // 0..63
    const int sq   = (tid & 3) ^ (srow & 3);         // swizzled source k-chunk
    int am  = row0 + srow;      if (am  > M - 1) am  = M - 1;
    int wn0 = col0 + srow;      if (wn0 > N - 1) wn0 = N - 1;
    int wn1 = col0 + 64 + srow; if (wn1 > N - 1) wn1 = N - 1;
    const long kbase = (long)kc * Kc + sq * 8;
    const ushort* gA  = Ah + bz * sA + (long)am  * lda + kbase;
    const ushort* gW0 = Wh + bz * sW + (long)wn0 * ldw + kbase;
    const ushort* gW1 = Wh + bz * sW + (long)wn1 * ldw + kbase;
    const ushort *gAl = nullptr, *gWl0 = nullptr, *gWl1 = nullptr;
    if constexpr (HASL) {
        if (sp) {
            gAl  = Al + bz * sA + (long)am  * lda + kbase;
            gWl0 = Wl + bz * sW + (long)wn0 * ldw + kbase;
            gWl1 = Wl + bz * sW + (long)wn1 * ldw + kbase;
        }
    }
    const int wb = (tid & 192) * 8;                  // wave-uniform LDS chunk base

    auto STAGE = [&](int buf, int k0) {
        gl16(gA + k0, &sA_h[buf][wb]);
        gl16(gW0 + k0, &sW_h[buf][wb]);
        gl16(gW1 + k0, &sW_h[buf][2048 + wb]);
        if constexpr (HASL) {
            if (sp) {
                gl16(gAl + k0, &sA_l[buf][wb]);
                gl16(gWl0 + k0, &sW_l[buf][wb]);
                gl16(gWl1 + k0, &sW_l[buf][2048 + wb]);
            }
        }
    };

    // ---- fragment read offsets (swizzled) ----
    const int lane = tid & 63, wv = tid >> 6;
    const int wr = (wv >> 1) * 32, wc = (wv & 1) * 64;
    const int fr = lane & 15;
    const int ksw = ((lane >> 4) ^ (lane & 3)) * 8;
    int aoff[2], boff[4];
#pragma unroll
    for (int mi = 0; mi < 2; ++mi) aoff[mi] = (wr + mi * 16 + fr) * 32 + ksw;
#pragma unroll
    for (int ni = 0; ni < 4; ++ni) boff[ni] = (wc + ni * 16 + fr) * 32 + ksw;

    f32x4 acc[2][4];
#pragma unroll
    for (int mi = 0; mi < 2; ++mi)
#pragma unroll
        for (int ni = 0; ni < 4; ++ni) acc[mi][ni] = (f32x4){0.f, 0.f, 0.f, 0.f};

    STAGE(0, 0);
    __syncthreads();
    int cur = 0;
    for (int k0 = 0; k0 < Kc; k0 += 32) {
        if (k0 + 32 < Kc) STAGE(cur ^ 1, k0 + 32);   // prefetch next K-tile

        short8 fa[2], fb[4];
#pragma unroll
        for (int mi = 0; mi < 2; ++mi) fa[mi] = *(const short8*)&sA_h[cur][aoff[mi]];
#pragma unroll
        for (int ni = 0; ni < 4; ++ni) fb[ni] = *(const short8*)&sW_h[cur][boff[ni]];
#pragma unroll
        for (int mi = 0; mi < 2; ++mi)
#pragma unroll
            for (int ni = 0; ni < 4; ++ni)
                acc[mi][ni] = __builtin_amdgcn_mfma_f32_16x16x32_bf16(fa[mi], fb[ni], acc[mi][ni], 0, 0, 0);
        if constexpr (HASL) {
            if (sp) {
                short8 ga[2], gb[4];
#pragma unroll
                for (int mi = 0; mi < 2; ++mi) ga[mi] = *(const short8*)&sA_l[cur][aoff[mi]];
#pragma unroll
                for (int ni = 0; ni < 4; ++ni) gb[ni] = *(const short8*)&sW_l[cur][boff[ni]];
#pragma unroll
                for (int mi = 0; mi < 2; ++mi)
#pragma unroll
                    for (int ni = 0; ni < 4; ++ni) {
                        acc[mi][ni] = __builtin_amdgcn_mfma_f32_16x16x32_bf16(fa[mi], gb[ni], acc[mi][ni], 0, 0, 0);
                        acc[mi][ni] = __builtin_amdgcn_mfma_f32_16x16x32_bf16(ga[mi], fb[ni], acc[mi][ni], 0, 0, 0);
                    }
            }
        }
        __syncthreads();   // drains prefetch vmcnt + protects buffer reuse
        cur ^= 1;
    }

    const int q4 = (lane >> 4) * 4;
    float g = 0.f;
    if constexpr (EPI == EPI_FINAL) g = gamma[0];
#pragma unroll
    for (int mi = 0; mi < 2; ++mi)
#pragma unroll
        for (int ni = 0; ni < 4; ++ni)
#pragma unroll
            for (int qi = 0; qi < 4; ++qi) {
                int m = row0 + wr + mi * 16 + q4 + qi;
                int n = col0 + wc + ni * 16 + fr;
                if (m >= M || n >= N) continue;
                float v = acc[mi][ni][qi];
                if (bias) v += bias[bz * sB + n];
                if constexpr (EPI == EPI_PART) {
                    fO[(long)blockIdx.z * sC + (long)m * ldc + n] = v;
                } else if constexpr (EPI == EPI_BF16) {
                    bO[(long)blockIdx.z * sC + (long)m * ldc + n] = f2bf(v);
                } else if constexpr (EPI == EPI_SPLIT) {
                    long o = (long)blockIdx.z * sC + (long)m * ldc + n;
                    ushort h, l; split2(v, h, l);
                    bO[o] = h; bO2[o] = l;
                } else {
                    int nimg = m / 49, p = m % 49;
                    long xi = (long)nimg * (2048 * 49) + (long)n * 49 + p;
                    float xv = ex[xi];
                    fout[xi] = (g * v + xv) * v + xv;
                }
            }
}

// prep: [0,8194) wconv ; [8194,10242) tx_split.
__global__ __launch_bounds__(256)
void prep(const float* c11, const float* c21, const float* conv3,
          const float* c22, const float* c12, const float* wval,
          const float* b_c11, const float* b_c21, const float* b_conv3,
          const float* x, const float* dX,
          ushort* Wg1h, ushort* Wg1l, ushort* C2h, ushort* C2l, ushort* Wvalb,
          float* bg1,
          ushort* Xth, ushort* Xtl, ushort* DXth, ushort* DXtl)
{
    __shared__ float tile[64][65];
    int b = blockIdx.x;
    int tid = threadIdx.x;
    if (b < 8194) {
        int e = b * 256 + tid;
        if (e < 1048576) {
            float v = e < 262144 ? c11[e] : e < 524288 ? c21[e - 262144] : conv3[e - 524288];
            ushort h, l; split2(v, h, l); Wg1h[e] = h; Wg1l[e] = l;
        } else if (e < 1572864) {
            int i = e - 1048576;
            float v = i < 262144 ? c22[i] : c12[i - 262144];
            ushort h, l; split2(v, h, l); C2h[i] = h; C2l[i] = l;
        } else if (e < 2097152) {
            int i = e - 1572864; Wvalb[i] = f2bf(wval[i]);
        } else if (e < 2097664) {
            int i = e - 2097152;
            bg1[i] = i < 128 ? b_c11[i] : i < 256 ? b_c21[i - 128] : b_conv3[i - 256];
        }
    } else {
        int local = b - 8194;                 // 0..2047
        int z = local >> 10;
        int rem = local & 1023;
        int n = rem & 31, c0 = (rem >> 5) * 64;
        const float* src = z ? dX : x;
        ushort* oh = z ? DXth : Xth;
        ushort* ol = z ? DXtl : Xtl;
        const float* s = src + (long)n * (2048 * 49) + (long)c0 * 49;
        for (int idx = tid; idx < 64 * 49; idx += 256)
            tile[idx / 49][idx % 49] = s[idx];
        __syncthreads();
        for (int idx = tid; idx < 49 * 64; idx += 256) {
            int p = idx >> 6, cl = idx & 63;
            float v = tile[cl][p];
            long o = (long)(n * 49 + p) * 2048 + c0 + cl;
            ushort h, l; split2(v, h, l);
            oh[o] = h; ol[o] = l;
        }
    }
}

// Fused: [0,3136) = r_g1 reduce (Q cols 0-127 / KmT scatter / V^T+pos);
//        [3136,3904) = wtrans (6 weight transposes into then-dead Xt/Wg1 space).
__global__ __launch_bounds__(256)
void rg1_wt(const float* __restrict__ P, const float* __restrict__ bg1,
            const float* __restrict__ pos,
            ushort* Qh, ushort* Ql, ushort* KmH, ushort* KmL, ushort* Vh,
            const float* w2u, const float* w2uY, const float* w2d, const float* w2dY,
            const float* wv, const float* w3,
            ushort* W2uTh, ushort* W2uTl, ushort* W2dTh, ushort* W2dTl,
            ushort* WvTh, ushort* WvTl, ushort* W3Th, ushort* W3Tl)
{
    __shared__ float tile[64][65];
    int blk = blockIdx.x;
    int tid = threadIdx.x;
    if (blk < 3136) {
        int idx = blk * 256 + tid;                 // 1568*512
        int m = idx >> 9, n = idx & 511;
        float v = P[idx] + P[802816 + idx] + P[1605632 + idx] + P[2408448 + idx] + bg1[n];
        int p = m % 49, img = m / 49;
        int f = img & 7, b = img >> 3;
        if (n < 128) {
            ushort h, l; split2(v, h, l);
            Qh[m * 256 + n] = h; Ql[m * 256 + n] = l;
        } else if (n < 256) {
            int c = n - 128;
            int flat = (p / 7) * 14336 + f * 1792 + (p % 7) * 256 + c;
            int ci = flat / 392, mm = flat % 392;
            long o = (long)b * 100352 + (long)mm * 256 + ci;
            ushort h, l; split2(v, h, l);
            KmH[o] = h; KmL[o] = l;
        } else {
            int c = n - 256;
            v += pos[f * 12544 + c * 49 + p];
            int s = m % 392;
            long o = (long)b * 106496 + (long)c * 416 + s;
            Vh[o] = f2bf(v);
            if (s < 24) Vh[o + 392] = 0;           // zero K-pad columns
        }
    } else {
        int t6 = blk - 3136;                       // 0..767
        int z = t6 >> 7, t = t6 & 127;
        const float* src; ushort *dh, *dl; int rows;
        switch (z) {
            case 0:  src = w2u;  dh = W2uTh;          dl = W2uTl;          rows = 2048; break;
            case 1:  src = w2uY; dh = W2uTh + 524288; dl = W2uTl + 524288; rows = 2048; break;
            case 2:  src = w2d;  dh = W2dTh;          dl = W2dTl;          rows = 256;  break;
            case 3:  src = w2dY; dh = W2dTh + 524288; dl = W2dTl + 524288; rows = 256;  break;
            case 4:  src = wv;   dh = WvTh;           dl = WvTl;           rows = 2048; break;
            default: src = w3;   dh = W3Th;           dl = W3Tl;           rows = 256;  break;
        }
        int cols = 524288 / rows;
        int tilesX = cols >> 6;
        int tx = t % tilesX, ty = t / tilesX;
        for (int i = tid; i < 4096; i += 256) {
            int r = i >> 6, c = i & 63;
            tile[r][c] = src[(long)(ty * 64 + r) * cols + tx * 64 + c];
        }
        __syncthreads();
        for (int i = tid; i < 4096; i += 256) {
            int c = i >> 6, r = i & 63;
            float v = tile[r][c];
            ushort h, l; split2(v, h, l);
            long o = (long)(tx * 64 + c) * rows + ty * 64 + r;
            dh[o] = h; dl[o] = l;
        }
    }
}

// GQK2 reduce (4 K-chunks + folded consts): j<128 -> K channel 128+j scatter into KmT;
// j>=128 -> Q col j.
__global__ __launch_bounds__(256)
void r_qk2(const float* __restrict__ P, const float* __restrict__ kc,
           ushort* Qh, ushort* Ql, ushort* KmH, ushort* KmL)
{
    int idx = blockIdx.x * 256 + threadIdx.x;      // 1568*256
    int m = idx >> 8, j = idx & 255;
    float v = P[idx] + P[401408 + idx] + P[802816 + idx] + P[1204224 + idx] + kc[j];
    ushort h, l; split2(v, h, l);
    if (j < 128) {
        int c = 128 + j;
        int p = m % 49, img = m / 49, f = img & 7, b = img >> 3;
        int flat = (p / 7) * 14336 + f * 1792 + (p % 7) * 256 + c;
        int ci = flat / 392, mm = flat % 392;
        long o = (long)b * 100352 + (long)mm * 256 + ci;
        KmH[o] = h; KmL[o] = l;
    } else {
        Qh[m * 256 + j] = h; Ql[m * 256 + j] = l;
    }
}

// Weight-chain split-K reduce: [2][16][128][256] -> split hi/lo [2][128][256].
// If kc != nullptr (A3 call): additionally fold the bias constants
//   kc_z[i] = A3_z[i]·b1d + A2_z[i]·b1u + A1_z[i]·b2d + C2_z[i]·b2u + bc_z[i]
__global__ __launch_bounds__(256)
void r_s(const float* __restrict__ P, ushort* __restrict__ Oh, ushort* __restrict__ Ol,
         const ushort* __restrict__ A1h, const ushort* __restrict__ A1l,
         const ushort* __restrict__ A2h, const ushort* __restrict__ A2l,
         const float* __restrict__ c22, const float* __restrict__ c12,
         const float* __restrict__ b1dX, const float* __restrict__ b1uX,
         const float* __restrict__ b2dX, const float* __restrict__ b2uX,
         const float* __restrict__ b1dY, const float* __restrict__ b1uY,
         const float* __restrict__ b2dY, const float* __restrict__ b2uY,
         const float* __restrict__ bc22, const float* __restrict__ bc12,
         float* __restrict__ kc)
{
    int tid = threadIdx.x;
    int blk = blockIdx.x;                          // = z*128 + i
    int idx = blk * 256 + tid;
    int br = idx >> 15, e = idx & 32767;
    const float* p = P + (long)br * 524288;
    float v = 0.f;
#pragma unroll
    for (int k = 0; k < 16; ++k) v += p[k * 32768 + e];
    ushort h, l; split2(v, h, l);
    Oh[idx] = h; Ol[idx] = l;

    if (kc) {
        int z = blk >> 7, i = blk & 127;
        const float* b1d = z ? b1dY : b1dX;
        const float* b1u = z ? b1uY : b1uX;
        const float* b2d = z ? b2dY : b2dX;
        const float* b2u = z ? b2uY : b2uX;
        const float* cw  = (z ? c12 : c22) + (long)i * 2048;
        const ushort* a1h = A1h + (long)blk * 256;
        const ushort* a1l = A1l + (long)blk * 256;
        const ushort* a2h = A2h + (long)blk * 2048;
        const ushort* a2l = A2l + (long)blk * 2048;
        float acc = v * b1d[tid];                                    // A3 term (c = tid)
        acc = fmaf(bf2f(a1h[tid]) + bf2f(a1l[tid]), b2d[tid], acc);  // A1 term
#pragma unroll
        for (int u = 0; u < 8; ++u) {
            int c = u * 256 + tid;
            acc = fmaf(bf2f(a2h[c]) + bf2f(a2l[c]), b1u[c], acc);
            acc = fmaf(cw[c], b2u[c], acc);
        }
        __shared__ float red[4];
        for (int off = 32; off; off >>= 1) acc += __shfl_down(acc, off, 64);
        if ((tid & 63) == 0) red[tid >> 6] = acc;
        __syncthreads();
        if (tid == 0)
            kc[blk] = red[0] + red[1] + red[2] + red[3] + (z ? bc12 : bc22)[i];
    }
}

// Fused attention: per block = 64 Q-rows x one batch. QK^T (3-pass split) with
// operands direct from global (L2-resident), in-register softmax (16-lane-group
// shfl), P -> LDS (stride 424), PV with V from global. O bf16 out.
__global__ __launch_bounds__(256)
void fattn(const ushort* __restrict__ Qh, const ushort* __restrict__ Ql,
           const ushort* __restrict__ Kmh, const ushort* __restrict__ Kml,
           const ushort* __restrict__ VT, ushort* __restrict__ O)
{
    __shared__ ushort Pl[4][16 * 424];
    const int b = blockIdx.y;
    const int r0 = blockIdx.x * 64;
    const int tid = threadIdx.x;
    const int lane = tid & 63, wv = tid >> 6;
    const int fr = lane & 15, kb = (lane >> 4) * 8;
    const int rw = r0 + wv * 16;
    const long base = (long)b * 100352;
    const long vbase = (long)b * 106496;

    // Q fragments (row = rw+fr, clamped; K = 256 -> 8 chunks of 32)
    int qr = rw + fr; if (qr > 391) qr = 391;
    const ushort* qph = Qh + base + (long)qr * 256 + kb;
    const ushort* qpl = Ql + base + (long)qr * 256 + kb;
    short8 qh[8], ql[8];
#pragma unroll
    for (int kf = 0; kf < 8; ++kf) {
        qh[kf] = *(const short8*)(qph + kf * 32);
        ql[kf] = *(const short8*)(qpl + kf * 32);
    }

    // logits: 26 col-frags of 16 (416 padded)
    f32x4 lg[26];
#pragma unroll
    for (int nf = 0; nf < 26; ++nf) {
        int kcol = nf * 16 + fr; if (kcol > 391) kcol = 391;
        const ushort* kph = Kmh + base + (long)kcol * 256 + kb;
        const ushort* kpl = Kml + base + (long)kcol * 256 + kb;
        f32x4 a = (f32x4){0.f, 0.f, 0.f, 0.f};
#pragma unroll
        for (int kf = 0; kf < 8; ++kf) {
            short8 bh = *(const short8*)(kph + kf * 32);
            short8 bl = *(const short8*)(kpl + kf * 32);
            a = __builtin_amdgcn_mfma_f32_16x16x32_bf16(qh[kf], bh, a, 0, 0, 0);
            a = __builtin_amdgcn_mfma_f32_16x16x32_bf16(qh[kf], bl, a, 0, 0, 0);
            a = __builtin_amdgcn_mfma_f32_16x16x32_bf16(ql[kf], bh, a, 0, 0, 0);
        }
        lg[nf] = a;
    }

    // mask pad cols (col = nf*16 + fr >= 392)
    if (fr >= 8) {
#pragma unroll
        for (int q = 0; q < 4; ++q) lg[24][q] = -1e30f;
    }
#pragma unroll
    for (int q = 0; q < 4; ++q) lg[25][q] = -1e30f;

    // softmax per row (row = (lane>>4)*4 + q; cols spread over the 16 fr-lanes)
    float inv[4];
#pragma unroll
    for (int q = 0; q < 4; ++q) {
        float m = -1e30f;
#pragma unroll
        for (int nf = 0; nf < 26; ++nf) m = fmaxf(m, lg[nf][q]);
        for (int off = 8; off; off >>= 1) m = fmaxf(m, __shfl_xor(m, off, 64));
        float s = 0.f;
#pragma unroll
        for (int nf = 0; nf < 26; ++nf) { float e = __expf(lg[nf][q] - m); lg[nf][q] = e; s += e; }
        for (int off = 8; off; off >>= 1) s += __shfl_xor(s, off, 64);
        inv[q] = 1.f / s;
    }

    // P -> per-wave LDS [16][424] bf16 (stride 424 avoids bank conflicts)
    ushort* pw = &Pl[wv][0];
#pragma unroll
    for (int nf = 0; nf < 26; ++nf)
#pragma unroll
        for (int q = 0; q < 4; ++q) {
            int rr = (lane >> 4) * 4 + q;
            pw[rr * 424 + nf * 16 + fr] = f2bf(lg[nf][q] * inv[q]);
        }
    __syncthreads();

    // PV: O[16 rows][256] = P[16][416] @ V^T ; V read direct from global (L2)
#pragma unroll
    for (int cf = 0; cf < 16; ++cf) {
        f32x4 o = (f32x4){0.f, 0.f, 0.f, 0.f};
        const ushort* vp = VT + vbase + (long)(cf * 16 + fr) * 416 + kb;
#pragma unroll
        for (int kf = 0; kf < 13; ++kf) {
            short8 pa = *(const short8*)&pw[fr * 424 + kf * 32 + kb];
            short8 vb = *(const short8*)(vp + kf * 32);
            o = __builtin_amdgcn_mfma_f32_16x16x32_bf16(pa, vb, o, 0, 0, 0);
        }
#pragma unroll
        for (int q = 0; q < 4; ++q) {
            int orow = rw + (lane >> 4) * 4 + q;
            if (orow < 392)
                O[base + (long)orow * 256 + cf * 16 + fr] = f2bf(o[q]);
        }
    }
}

extern "C" void kernel_launch(void* const* d_in, const int* in_sizes, int n_in,
                              void* d_out, int out_size, void* d_ws, size_t ws_size,
                              hipStream_t stream)
{
    const float* x        = (const float*)d_in[0];
    const float* domainX  = (const float*)d_in[1];
    const float* w_conv3  = (const float*)d_in[5];
    const float* b_conv3  = (const float*)d_in[6];
    const float* w_value  = (const float*)d_in[7];
    const float* b_value  = (const float*)d_in[8];
    const float* b_l1down   = (const float*)d_in[9];
    const float* b_l1up     = (const float*)d_in[10];
    const float* b_l1down_Y = (const float*)d_in[11];
    const float* b_l1up_Y   = (const float*)d_in[12];
    const float* w_l2down   = (const float*)d_in[13];
    const float* b_l2down   = (const float*)d_in[14];
    const float* w_l2up     = (const float*)d_in[15];
    const float* b_l2up     = (const float*)d_in[16];
    const float* w_l2down_Y = (const float*)d_in[17];
    const float* b_l2down_Y = (const float*)d_in[18];
    const float* w_l2up_Y   = (const float*)d_in[19];
    const float* b_l2up_Y   = (const float*)d_in[20];
    const float* w_c11 = (const float*)d_in[21];
    const float* b_c11 = (const float*)d_in[22];
    const float* w_c12 = (const float*)d_in[23];
    const float* b_c12 = (const float*)d_in[24];
    const float* w_c21 = (const float*)d_in[25];
    const float* b_c21 = (const float*)d_in[26];
    const float* w_c22 = (const float*)d_in[27];
    const float* b_c22 = (const float*)d_in[28];
    const float* pos   = (const float*)d_in[29];
    const float* gamma = (const float*)d_in[30];
    float* out = (float*)d_out;

    ushort* U = (ushort*)d_ws;
    float*  Fp = (float*)d_ws;

    // ---- liveness-packed workspace (ushort elems unless f-prefixed; 46.4 MB) ----
    const long oXt_h   = 0;          // dies after G1
    const long oXt_l   = 3211264;
    const long oDXt_h  = 6422528;    // dies after GQK2
    const long oDXt_l  = 9633792;
    const long oWg1_h  = 12845056;   // dies after G1
    const long oWg1_l  = 13893632;
    const long oWval   = 14942208;   // lives to final
    const long fPG1    = 7733248;    // f32 [4][1568][512] @ush 15466496..21889024
    const long oC2_h   = 21889024;   // [2][128][2048] c22|c12
    const long oC2_l   = 22413312;
    // after rg1_wt (overlay dead Xt):
    const long oQ_h    = 0;
    const long oQ_l    = 401408;
    const long oKm_h   = 802816;
    const long oKm_l   = 1204224;
    const long oVT     = 1605632;    // [4][256][416]
    const long oW2uT_h = 2031616;    // [2][256][2048]
    const long oW2uT_l = 3080192;
    const long oW2dT_h = 4128768;    // [2][2048][256]
    const long oW2dT_l = 5177344;
    // overlay dead Wg1:
    const long oWvT_h  = 12845056;   // [256][2048]
    const long oWvT_l  = 13369344;
    const long oW3T_h  = 13893632;   // [2048][256]
    const long oW3T_l  = 14417920;
    // overlay dead PG1:
    const long fSpart  = 7733248;    // f32 [32][128][256]
    const long oA1_h   = 17563648;   // [2][128][256]
    const long oA1_l   = 17629184;
    const long oA2_h   = 17694720;   // [2][128][2048]
    const long oA2_l   = 18219008;
    const long oA3_h   = 18743296;
    const long oA3_l   = 18808832;
    const long oM_h    = 18874368;   // [2][128][2048] = [256][2048]
    const long oM_l    = 19398656;
    const long fPG2    = 9961472;    // f32 [4][1568][256] @ush 19922944..23134208
    // overlay dead DXt:
    const long oO      = 9683968;    // [1568][256]
    // smalls:
    const long fbg1    = 11600000;   // 512
    const long fkc     = 11600512;   // 256

    // 1. prep: weight conversions + activation transposes
    prep<<<dim3(10242), 256, 0, stream>>>(
        w_c11, w_c21, w_conv3, w_c22, w_c12, w_value,
        b_c11, b_c21, b_conv3, x, domainX,
        U + oWg1_h, U + oWg1_l, U + oC2_h, U + oC2_l, U + oWval, Fp + fbg1,
        U + oXt_h, U + oXt_l, U + oDXt_h, U + oDXt_l);
    // 2. G1: Xt @ [c11|c21|conv3]^T; Q/K blocks 3-pass, V blocks 1-pass; split-K 4
    gmm<EPI_PART, 2><<<dim3(4, 25, 4), 256, 0, stream>>>(
        U + oXt_h, U + oXt_l, 2048, 0, U + oWg1_h, U + oWg1_l, 2048, 0,
        nullptr, 0, 4, 512, Fp + fPG1, nullptr, nullptr, 512, 802816L, TOKENS, 512,
        nullptr, nullptr, nullptr);
    // 3. fused r_g1 + wtrans (Xt/Wg1 dead after G1 -> overlay legal)
    rg1_wt<<<dim3(3904), 256, 0, stream>>>(Fp + fPG1, Fp + fbg1, pos,
        U + oQ_h, U + oQ_l, U + oKm_h, U + oKm_l, U + oVT,
        w_l2up, w_l2up_Y, w_l2down, w_l2down_Y, w_value, w_conv3,
        U + oW2uT_h, U + oW2uT_l, U + oW2dT_h, U + oW2dT_l,
        U + oWvT_h, U + oWvT_l, U + oW3T_h, U + oW3T_l);
    // 4. S1 = [c22|c12] @ W2uT^T  (K=2048, split-K 16)
    gmm<EPI_PART, 1><<<dim3(2, 2, 32), 256, 0, stream>>>(
        U + oC2_h, U + oC2_l, 2048, 262144, U + oW2uT_h, U + oW2uT_l, 2048, 524288,
        nullptr, 0, 16, 128, Fp + fSpart, nullptr, nullptr, 256, 32768L, 128, 256,
        nullptr, nullptr, nullptr);
    r_s<<<dim3(256), 256, 0, stream>>>(Fp + fSpart, U + oA1_h, U + oA1_l,
        nullptr, nullptr, nullptr, nullptr, nullptr, nullptr,
        nullptr, nullptr, nullptr, nullptr, nullptr, nullptr, nullptr, nullptr,
        nullptr, nullptr, nullptr);
    // 5. S2 = A1 @ W2dT^T  (K=256, direct split out)
    gmm<EPI_SPLIT, 1><<<dim3(16, 2, 2), 256, 0, stream>>>(
        U + oA1_h, U + oA1_l, 256, 32768, U + oW2dT_h, U + oW2dT_l, 256, 524288,
        nullptr, 0, 1, 256, nullptr, U + oA2_h, U + oA2_l, 2048, 262144L, 128, 2048,
        nullptr, nullptr, nullptr);
    // 6. S3 = A2 @ WvT^T  (K=2048, split-K 16)
    gmm<EPI_PART, 1><<<dim3(2, 2, 32), 256, 0, stream>>>(
        U + oA2_h, U + oA2_l, 2048, 262144, U + oWvT_h, U + oWvT_l, 2048, 0,
        nullptr, 0, 16, 128, Fp + fSpart, nullptr, nullptr, 256, 32768L, 128, 256,
        nullptr, nullptr, nullptr);
    // 7. r_s(A3) + fused kc constants
    r_s<<<dim3(256), 256, 0, stream>>>(Fp + fSpart, U + oA3_h, U + oA3_l,
        U + oA1_h, U + oA1_l, U + oA2_h, U + oA2_l, w_c22, w_c12,
        b_l1down, b_l1up, b_l2down, b_l2up,
        b_l1down_Y, b_l1up_Y, b_l2down_Y, b_l2up_Y,
        b_c22, b_c12, Fp + fkc);
    // 8. S4 = A3 @ W3T^T -> M = [M_X | M_Q]  (K=256, direct split out)
    gmm<EPI_SPLIT, 1><<<dim3(16, 2, 2), 256, 0, stream>>>(
        U + oA3_h, U + oA3_l, 256, 32768, U + oW3T_h, U + oW3T_l, 256, 0,
        nullptr, 0, 1, 256, nullptr, U + oM_h, U + oM_l, 2048, 262144L, 128, 2048,
        nullptr, nullptr, nullptr);
    // 9. GQK2 = DXt @ M^T  (K=2048, 3-pass, split-K 4)
    gmm<EPI_PART, 1><<<dim3(2, 25, 4), 256, 0, stream>>>(
        U + oDXt_h, U + oDXt_l, 2048, 0, U + oM_h, U + oM_l, 2048, 0,
        nullptr, 0, 4, 512, Fp + fPG2, nullptr, nullptr, 256, 401408L, TOKENS, 256,
        nullptr, nullptr, nullptr);
    // 10. reduce -> K channels 128+ (KmT scatter), Q cols 128+
    r_qk2<<<dim3(1568), 256, 0, stream>>>(Fp + fPG2, Fp + fkc,
        U + oQ_h, U + oQ_l, U + oKm_h, U + oKm_l);
    // 11. fused attention: logits (3-pass) + softmax + PV -> O bf16
    fattn<<<dim3(7, 4), 256, 0, stream>>>(
        U + oQ_h, U + oQ_l, U + oKm_h, U + oKm_l, U + oVT, U + oO);
    // 12. final: z = O @ w_value^T + b_value ; out = (g*z + x)*z + x
    gmm<EPI_FINAL, 0><<<dim3(16, 25, 1), 256, 0, stream>>>(
        U + oO, nullptr, 256, 0, U + oWval, nullptr, 256, 0,
        b_value, 0, 1, 256, nullptr, nullptr, nullptr, 0, 0L, TOKENS, 2048,
        x, gamma, out);
}

// Round 9
// 228.335 us; speedup vs baseline: 1.0065x; 1.0065x over previous
//
#include <hip/hip_runtime.h>
#include <hip/hip_bf16.h>

// ---------------------------------------------------------------------------
// SCSAttention on MI355X, round 9.
//   - fattn fixed: __launch_bounds__(256,1) (r8 spilled at VGPR cap 116).
//   - fresh flat workspace (~98 MB of the 256 MB d_ws) -> no overlays; wtrans
//     fused into prep safely.
//   - split-K 8 on G1 and GQK2 for occupancy.
// Sensitive path (Q/K/logits) = bf16x2 hi/lo 3-pass. 13 launches.
// ---------------------------------------------------------------------------

typedef __attribute__((ext_vector_type(8))) short short8;
typedef __attribute__((ext_vector_type(4))) float f32x4;

#define TOKENS 1568

__device__ __forceinline__ ushort f2bf(float f) {
    uint32_t u = __float_as_uint(f);
    u += 0x7fffu + ((u >> 16) & 1u);   // RNE
    return (ushort)(u >> 16);
}
__device__ __forceinline__ float bf2f(ushort h) { return __uint_as_float(((uint32_t)h) << 16); }
__device__ __forceinline__ void split2(float v, ushort& h, ushort& l) {
    h = f2bf(v); l = f2bf(v - bf2f(h));
}

__device__ __forceinline__ void gl16(const void* g, void* l) {
    __builtin_amdgcn_global_load_lds(
        (const __attribute__((address_space(1))) unsigned int*)g,
        (__attribute__((address_space(3))) unsigned int*)l, 16, 0, 0);
}

#define EPI_PART  0
#define EPI_BF16  1
#define EPI_SPLIT 2
#define EPI_FINAL 3

// C[m][n] = sum_k A[m][k]*W[n][k]; tile 64(M)x128(N), BK=32, 4 waves (2x2),
// wave = 32x64 = 2x4 16x16 frags. SPL: 0 plain, 1 split 3-pass, 2 split iff blockIdx.x<2.
// Double-buffered LDS: STAGE(next) issued before MFMA(cur), one barrier per K-step.
template<int EPI, int SPL>
__global__ __launch_bounds__(256)
void gmm(const ushort* __restrict__ Ah, const ushort* __restrict__ Al, int lda, long sA,
         const ushort* __restrict__ Wh, const ushort* __restrict__ Wl, int ldw, long sW,
         const float* __restrict__ bias, int sB,
         int nkc, int Kc,
         float* __restrict__ fO, ushort* __restrict__ bO, ushort* __restrict__ bO2,
         int ldc, long sC, int M, int N,
         const float* __restrict__ ex, const float* __restrict__ gamma,
         float* __restrict__ fout)
{
    constexpr bool HASL = (SPL >= 1);
    __shared__ __align__(16) ushort sA_h[2][64 * 32];
    __shared__ __align__(16) ushort sW_h[2][128 * 32];
    __shared__ __align__(16) ushort sA_l[HASL ? 2 : 1][HASL ? 64 * 32 : 8];
    __shared__ __align__(16) ushort sW_l[HASL ? 2 : 1][HASL ? 128 * 32 : 8];

    const int tid = threadIdx.x;
    const int bz = blockIdx.z / nkc;
    const int kc = blockIdx.z % nkc;
    const int row0 = blockIdx.y * 64, col0 = blockIdx.x * 128;
    const bool sp = (SPL == 1) || (SPL == 2 && blockIdx.x < 2);

    const int srow = tid >> 2;                       // 0..63
    const int sq   = (tid & 3) ^ (srow & 3);         // swizzled source k-chunk
    int am  = row0 + srow;      if (am  > M - 1) am  = M - 1;
    int wn0 = col0 + srow;      if (wn0 > N - 1) wn0 = N - 1;
    int wn1 = col0 + 64 + srow; if (wn1 > N - 1) wn1 = N - 1;
    const long kbase = (long)kc * Kc + sq * 8;
    const ushort* gA  = Ah + bz * sA + (long)am  * lda + kbase;
    const ushort* gW0 = Wh + bz * sW + (long)wn0 * ldw + kbase;
    const ushort* gW1 = Wh + bz * sW + (long)wn1 * ldw + kbase;
    const ushort *gAl = nullptr, *gWl0 = nullptr, *gWl1 = nullptr;
    if constexpr (HASL) {
        if (sp) {
            gAl  = Al + bz * sA + (long)am  * lda + kbase;
            gWl0 = Wl + bz * sW + (long)wn0 * ldw + kbase;
            gWl1 = Wl + bz * sW + (long)wn1 * ldw + kbase;
        }
    }
    const int wb = (tid & 192) * 8;                  // wave-uniform LDS chunk base

    auto STAGE = [&](int buf, int k0) {
        gl16(gA + k0, &sA_h[buf][wb]);
        gl16(gW0 + k0, &sW_h[buf][wb]);
        gl16(gW1 + k0, &sW_h[buf][2048 + wb]);
        if constexpr (HASL) {
            if (sp) {
                gl16(gAl + k0, &sA_l[buf][wb]);
                gl16(gWl0 + k0, &sW_l[buf][wb]);
                gl16(gWl1 + k0, &sW_l[buf][2048 + wb]);
            }
        }
    };

    const int lane = tid & 63, wv = tid >> 6;
    const int wr = (wv >> 1) * 32, wc = (wv & 1) * 64;
    const int fr = lane & 15;
    const int ksw = ((lane >> 4) ^ (lane & 3)) * 8;
    int aoff[2], boff[4];
#pragma unroll
    for (int mi = 0; mi < 2; ++mi) aoff[mi] = (wr + mi * 16 + fr) * 32 + ksw;
#pragma unroll
    for (int ni = 0; ni < 4; ++ni) boff[ni] = (wc + ni * 16 + fr) * 32 + ksw;

    f32x4 acc[2][4];
#pragma unroll
    for (int mi = 0; mi < 2; ++mi)
#pragma unroll
        for (int ni = 0; ni < 4; ++ni) acc[mi][ni] = (f32x4){0.f, 0.f, 0.f, 0.f};

    STAGE(0, 0);
    __syncthreads();
    int cur = 0;
    for (int k0 = 0; k0 < Kc; k0 += 32) {
        if (k0 + 32 < Kc) STAGE(cur ^ 1, k0 + 32);   // prefetch next K-tile

        short8 fa[2], fb[4];
#pragma unroll
        for (int mi = 0; mi < 2; ++mi) fa[mi] = *(const short8*)&sA_h[cur][aoff[mi]];
#pragma unroll
        for (int ni = 0; ni < 4; ++ni) fb[ni] = *(const short8*)&sW_h[cur][boff[ni]];
#pragma unroll
        for (int mi = 0; mi < 2; ++mi)
#pragma unroll
            for (int ni = 0; ni < 4; ++ni)
                acc[mi][ni] = __builtin_amdgcn_mfma_f32_16x16x32_bf16(fa[mi], fb[ni], acc[mi][ni], 0, 0, 0);
        if constexpr (HASL) {
            if (sp) {
                short8 ga[2], gb[4];
#pragma unroll
                for (int mi = 0; mi < 2; ++mi) ga[mi] = *(const short8*)&sA_l[cur][aoff[mi]];
#pragma unroll
                for (int ni = 0; ni < 4; ++ni) gb[ni] = *(const short8*)&sW_l[cur][boff[ni]];
#pragma unroll
                for (int mi = 0; mi < 2; ++mi)
#pragma unroll
                    for (int ni = 0; ni < 4; ++ni) {
                        acc[mi][ni] = __builtin_amdgcn_mfma_f32_16x16x32_bf16(fa[mi], gb[ni], acc[mi][ni], 0, 0, 0);
                        acc[mi][ni] = __builtin_amdgcn_mfma_f32_16x16x32_bf16(ga[mi], fb[ni], acc[mi][ni], 0, 0, 0);
                    }
            }
        }
        __syncthreads();
        cur ^= 1;
    }

    const int q4 = (lane >> 4) * 4;
    float g = 0.f;
    if constexpr (EPI == EPI_FINAL) g = gamma[0];
#pragma unroll
    for (int mi = 0; mi < 2; ++mi)
#pragma unroll
        for (int ni = 0; ni < 4; ++ni)
#pragma unroll
            for (int qi = 0; qi < 4; ++qi) {
                int m = row0 + wr + mi * 16 + q4 + qi;
                int n = col0 + wc + ni * 16 + fr;
                if (m >= M || n >= N) continue;
                float v = acc[mi][ni][qi];
                if (bias) v += bias[bz * sB + n];
                if constexpr (EPI == EPI_PART) {
                    fO[(long)blockIdx.z * sC + (long)m * ldc + n] = v;
                } else if constexpr (EPI == EPI_BF16) {
                    bO[(long)blockIdx.z * sC + (long)m * ldc + n] = f2bf(v);
                } else if constexpr (EPI == EPI_SPLIT) {
                    long o = (long)blockIdx.z * sC + (long)m * ldc + n;
                    ushort h, l; split2(v, h, l);
                    bO[o] = h; bO2[o] = l;
                } else {
                    int nimg = m / 49, p = m % 49;
                    long xi = (long)nimg * (2048 * 49) + (long)n * 49 + p;
                    float xv = ex[xi];
                    fout[xi] = (g * v + xv) * v + xv;
                }
            }
}

// prep: [0,8194) wconv ; [8194,10242) tx_split ; [10242,11010) wtrans.
// Safe fusion: all outputs live in fresh, non-overlapping regions.
__global__ __launch_bounds__(256)
void prep(const float* c11, const float* c21, const float* conv3,
          const float* c22, const float* c12, const float* wval,
          const float* b_c11, const float* b_c21, const float* b_conv3,
          const float* x, const float* dX,
          const float* w2u, const float* w2uY, const float* w2d, const float* w2dY,
          const float* wv, const float* w3,
          ushort* Wg1h, ushort* Wg1l, ushort* C2h, ushort* C2l, ushort* Wvalb,
          float* bg1,
          ushort* Xth, ushort* Xtl, ushort* DXth, ushort* DXtl,
          ushort* W2uTh, ushort* W2uTl, ushort* W2dTh, ushort* W2dTl,
          ushort* WvTh, ushort* WvTl, ushort* W3Th, ushort* W3Tl)
{
    __shared__ float tile[64][65];
    int b = blockIdx.x;
    int tid = threadIdx.x;
    if (b < 8194) {
        int e = b * 256 + tid;
        if (e < 1048576) {
            float v = e < 262144 ? c11[e] : e < 524288 ? c21[e - 262144] : conv3[e - 524288];
            ushort h, l; split2(v, h, l); Wg1h[e] = h; Wg1l[e] = l;
        } else if (e < 1572864) {
            int i = e - 1048576;
            float v = i < 262144 ? c22[i] : c12[i - 262144];
            ushort h, l; split2(v, h, l); C2h[i] = h; C2l[i] = l;
        } else if (e < 2097152) {
            int i = e - 1572864; Wvalb[i] = f2bf(wval[i]);
        } else if (e < 2097664) {
            int i = e - 2097152;
            bg1[i] = i < 128 ? b_c11[i] : i < 256 ? b_c21[i - 128] : b_conv3[i - 256];
        }
    } else if (b < 10242) {
        int local = b - 8194;                 // 0..2047
        int z = local >> 10;
        int rem = local & 1023;
        int n = rem & 31, c0 = (rem >> 5) * 64;
        const float* src = z ? dX : x;
        ushort* oh = z ? DXth : Xth;
        ushort* ol = z ? DXtl : Xtl;
        const float* s = src + (long)n * (2048 * 49) + (long)c0 * 49;
        for (int idx = tid; idx < 64 * 49; idx += 256)
            tile[idx / 49][idx % 49] = s[idx];
        __syncthreads();
        for (int idx = tid; idx < 49 * 64; idx += 256) {
            int p = idx >> 6, cl = idx & 63;
            float v = tile[cl][p];
            long o = (long)(n * 49 + p) * 2048 + c0 + cl;
            ushort h, l; split2(v, h, l);
            oh[o] = h; ol[o] = l;
        }
    } else {
        int local = b - 10242;                // 0..767
        int z = local >> 7, t = local & 127;
        const float* src; ushort *dh, *dl; int rows;
        switch (z) {
            case 0:  src = w2u;  dh = W2uTh;          dl = W2uTl;          rows = 2048; break;
            case 1:  src = w2uY; dh = W2uTh + 524288; dl = W2uTl + 524288; rows = 2048; break;
            case 2:  src = w2d;  dh = W2dTh;          dl = W2dTl;          rows = 256;  break;
            case 3:  src = w2dY; dh = W2dTh + 524288; dl = W2dTl + 524288; rows = 256;  break;
            case 4:  src = wv;   dh = WvTh;           dl = WvTl;           rows = 2048; break;
            default: src = w3;   dh = W3Th;           dl = W3Tl;           rows = 256;  break;
        }
        int cols = 524288 / rows;
        int tilesX = cols >> 6;
        int tx = t % tilesX, ty = t / tilesX;
        for (int i = tid; i < 4096; i += 256) {
            int r = i >> 6, c = i & 63;
            tile[r][c] = src[(long)(ty * 64 + r) * cols + tx * 64 + c];
        }
        __syncthreads();
        for (int i = tid; i < 4096; i += 256) {
            int c = i >> 6, r = i & 63;
            float v = tile[r][c];
            ushort h, l; split2(v, h, l);
            long o = (long)(tx * 64 + c) * rows + ty * 64 + r;
            dh[o] = h; dl[o] = l;
        }
    }
}

// G1 reduce (8 K-chunks): n<128 -> Q cols 0-127 split; n<256 -> K scatter into KmT;
// n>=256 -> V (+pos) transposed [b][c][416], pad-zeroed.
__global__ __launch_bounds__(256)
void r_g1(const float* __restrict__ P, const float* __restrict__ bg1,
          const float* __restrict__ pos,
          ushort* Qh, ushort* Ql, ushort* KmH, ushort* KmL, ushort* Vh)
{
    int idx = blockIdx.x * 256 + threadIdx.x;      // 1568*512
    int m = idx >> 9, n = idx & 511;
    float v = bg1[n];
#pragma unroll
    for (int k = 0; k < 8; ++k) v += P[(long)k * 802816 + idx];
    int p = m % 49, img = m / 49;
    int f = img & 7, b = img >> 3;
    if (n < 128) {
        ushort h, l; split2(v, h, l);
        Qh[m * 256 + n] = h; Ql[m * 256 + n] = l;
    } else if (n < 256) {
        int c = n - 128;
        int flat = (p / 7) * 14336 + f * 1792 + (p % 7) * 256 + c;
        int ci = flat / 392, mm = flat % 392;
        long o = (long)b * 100352 + (long)mm * 256 + ci;
        ushort h, l; split2(v, h, l);
        KmH[o] = h; KmL[o] = l;
    } else {
        int c = n - 256;
        v += pos[f * 12544 + c * 49 + p];
        int s = m % 392;
        long o = (long)b * 106496 + (long)c * 416 + s;
        Vh[o] = f2bf(v);
        if (s < 24) Vh[o + 392] = 0;               // zero K-pad columns
    }
}

// GQK2 reduce (8 K-chunks + folded consts): j<128 -> K channel 128+j scatter into KmT;
// j>=128 -> Q col j.
__global__ __launch_bounds__(256)
void r_qk2(const float* __restrict__ P, const float* __restrict__ kc,
           ushort* Qh, ushort* Ql, ushort* KmH, ushort* KmL)
{
    int idx = blockIdx.x * 256 + threadIdx.x;      // 1568*256
    int m = idx >> 8, j = idx & 255;
    float v = kc[j];
#pragma unroll
    for (int k = 0; k < 8; ++k) v += P[(long)k * 401408 + idx];
    ushort h, l; split2(v, h, l);
    if (j < 128) {
        int c = 128 + j;
        int p = m % 49, img = m / 49, f = img & 7, b = img >> 3;
        int flat = (p / 7) * 14336 + f * 1792 + (p % 7) * 256 + c;
        int ci = flat / 392, mm = flat % 392;
        long o = (long)b * 100352 + (long)mm * 256 + ci;
        KmH[o] = h; KmL[o] = l;
    } else {
        Qh[m * 256 + j] = h; Ql[m * 256 + j] = l;
    }
}

// Weight-chain split-K reduce: [2][16][128][256] -> split hi/lo [2][128][256].
// If kc != nullptr (A3 call): additionally fold the bias constants
//   kc_z[i] = A3_z[i]·b1d + A2_z[i]·b1u + A1_z[i]·b2d + C2_z[i]·b2u + bc_z[i]
__global__ __launch_bounds__(256)
void r_s(const float* __restrict__ P, ushort* __restrict__ Oh, ushort* __restrict__ Ol,
         const ushort* __restrict__ A1h, const ushort* __restrict__ A1l,
         const ushort* __restrict__ A2h, const ushort* __restrict__ A2l,
         const float* __restrict__ c22, const float* __restrict__ c12,
         const float* __restrict__ b1dX, const float* __restrict__ b1uX,
         const float* __restrict__ b2dX, const float* __restrict__ b2uX,
         const float* __restrict__ b1dY, const float* __restrict__ b1uY,
         const float* __restrict__ b2dY, const float* __restrict__ b2uY,
         const float* __restrict__ bc22, const float* __restrict__ bc12,
         float* __restrict__ kc)
{
    int tid = threadIdx.x;
    int blk = blockIdx.x;                          // = z*128 + i
    int idx = blk * 256 + tid;
    int br = idx >> 15, e = idx & 32767;
    const float* p = P + (long)br * 524288;
    float v = 0.f;
#pragma unroll
    for (int k = 0; k < 16; ++k) v += p[k * 32768 + e];
    ushort h, l; split2(v, h, l);
    Oh[idx] = h; Ol[idx] = l;

    if (kc) {
        int z = blk >> 7, i = blk & 127;
        const float* b1d = z ? b1dY : b1dX;
        const float* b1u = z ? b1uY : b1uX;
        const float* b2d = z ? b2dY : b2dX;
        const float* b2u = z ? b2uY : b2uX;
        const float* cw  = (z ? c12 : c22) + (long)i * 2048;
        const ushort* a1h = A1h + (long)blk * 256;
        const ushort* a1l = A1l + (long)blk * 256;
        const ushort* a2h = A2h + (long)blk * 2048;
        const ushort* a2l = A2l + (long)blk * 2048;
        float acc = v * b1d[tid];                                    // A3 term (c = tid)
        acc = fmaf(bf2f(a1h[tid]) + bf2f(a1l[tid]), b2d[tid], acc);  // A1 term
#pragma unroll
        for (int u = 0; u < 8; ++u) {
            int c = u * 256 + tid;
            acc = fmaf(bf2f(a2h[c]) + bf2f(a2l[c]), b1u[c], acc);
            acc = fmaf(cw[c], b2u[c], acc);
        }
        __shared__ float red[4];
        for (int off = 32; off; off >>= 1) acc += __shfl_down(acc, off, 64);
        if ((tid & 63) == 0) red[tid >> 6] = acc;
        __syncthreads();
        if (tid == 0)
            kc[blk] = red[0] + red[1] + red[2] + red[3] + (z ? bc12 : bc22)[i];
    }
}

// Fused attention (r8 math, fixed occupancy annotation): per block = 64 Q-rows x
// one batch. QK^T 3-pass from global (L2-resident), in-register softmax,
// P -> LDS, PV with V from global. __launch_bounds__(256,1): the logits live
// in ~200 VGPRs — r8's default cap (116) spilled them to scratch (80 us).
__global__ __launch_bounds__(256, 1)
void fattn(const ushort* __restrict__ Qh, const ushort* __restrict__ Ql,
           const ushort* __restrict__ Kmh, const ushort* __restrict__ Kml,
           const ushort* __restrict__ VT, ushort* __restrict__ O)
{
    __shared__ ushort Pl[4][16 * 424];
    const int b = blockIdx.y;
    const int r0 = blockIdx.x * 64;
    const int tid = threadIdx.x;
    const int lane = tid & 63, wv = tid >> 6;
    const int fr = lane & 15, kb = (lane >> 4) * 8;
    const int rw = r0 + wv * 16;
    const long base = (long)b * 100352;
    const long vbase = (long)b * 106496;

    int qr = rw + fr; if (qr > 391) qr = 391;
    const ushort* qph = Qh + base + (long)qr * 256 + kb;
    const ushort* qpl = Ql + base + (long)qr * 256 + kb;
    short8 qh[8], ql[8];
#pragma unroll
    for (int kf = 0; kf < 8; ++kf) {
        qh[kf] = *(const short8*)(qph + kf * 32);
        ql[kf] = *(const short8*)(qpl + kf * 32);
    }

    f32x4 lg[26];
#pragma unroll
    for (int nf = 0; nf < 26; ++nf) {
        int kcol = nf * 16 + fr; if (kcol > 391) kcol = 391;
        const ushort* kph = Kmh + base + (long)kcol * 256 + kb;
        const ushort* kpl = Kml + base + (long)kcol * 256 + kb;
        f32x4 a = (f32x4){0.f, 0.f, 0.f, 0.f};
#pragma unroll
        for (int kf = 0; kf < 8; ++kf) {
            short8 bh = *(const short8*)(kph + kf * 32);
            short8 bl = *(const short8*)(kpl + kf * 32);
            a = __builtin_amdgcn_mfma_f32_16x16x32_bf16(qh[kf], bh, a, 0, 0, 0);
            a = __builtin_amdgcn_mfma_f32_16x16x32_bf16(qh[kf], bl, a, 0, 0, 0);
            a = __builtin_amdgcn_mfma_f32_16x16x32_bf16(ql[kf], bh, a, 0, 0, 0);
        }
        lg[nf] = a;
    }

    if (fr >= 8) {
#pragma unroll
        for (int q = 0; q < 4; ++q) lg[24][q] = -1e30f;
    }
#pragma unroll
    for (int q = 0; q < 4; ++q) lg[25][q] = -1e30f;

    float inv[4];
#pragma unroll
    for (int q = 0; q < 4; ++q) {
        float m = -1e30f;
#pragma unroll
        for (int nf = 0; nf < 26; ++nf) m = fmaxf(m, lg[nf][q]);
        for (int off = 8; off; off >>= 1) m = fmaxf(m, __shfl_xor(m, off, 64));
        float s = 0.f;
#pragma unroll
        for (int nf = 0; nf < 26; ++nf) { float e = __expf(lg[nf][q] - m); lg[nf][q] = e; s += e; }
        for (int off = 8; off; off >>= 1) s += __shfl_xor(s, off, 64);
        inv[q] = 1.f / s;
    }

    ushort* pw = &Pl[wv][0];
#pragma unroll
    for (int nf = 0; nf < 26; ++nf)
#pragma unroll
        for (int q = 0; q < 4; ++q) {
            int rr = (lane >> 4) * 4 + q;
            pw[rr * 424 + nf * 16 + fr] = f2bf(lg[nf][q] * inv[q]);
        }
    __syncthreads();

#pragma unroll
    for (int cf = 0; cf < 16; ++cf) {
        f32x4 o = (f32x4){0.f, 0.f, 0.f, 0.f};
        const ushort* vp = VT + vbase + (long)(cf * 16 + fr) * 416 + kb;
#pragma unroll
        for (int kf = 0; kf < 13; ++kf) {
            short8 pa = *(const short8*)&pw[fr * 424 + kf * 32 + kb];
            short8 vb = *(const short8*)(vp + kf * 32);
            o = __builtin_amdgcn_mfma_f32_16x16x32_bf16(pa, vb, o, 0, 0, 0);
        }
#pragma unroll
        for (int q = 0; q < 4; ++q) {
            int orow = rw + (lane >> 4) * 4 + q;
            if (orow < 392)
                O[base + (long)orow * 256 + cf * 16 + fr] = f2bf(o[q]);
        }
    }
}

extern "C" void kernel_launch(void* const* d_in, const int* in_sizes, int n_in,
                              void* d_out, int out_size, void* d_ws, size_t ws_size,
                              hipStream_t stream)
{
    const float* x        = (const float*)d_in[0];
    const float* domainX  = (const float*)d_in[1];
    const float* w_conv3  = (const float*)d_in[5];
    const float* b_conv3  = (const float*)d_in[6];
    const float* w_value  = (const float*)d_in[7];
    const float* b_value  = (const float*)d_in[8];
    const float* b_l1down   = (const float*)d_in[9];
    const float* b_l1up     = (const float*)d_in[10];
    const float* b_l1down_Y = (const float*)d_in[11];
    const float* b_l1up_Y   = (const float*)d_in[12];
    const float* w_l2down   = (const float*)d_in[13];
    const float* b_l2down   = (const float*)d_in[14];
    const float* w_l2up     = (const float*)d_in[15];
    const float* b_l2up     = (const float*)d_in[16];
    const float* w_l2down_Y = (const float*)d_in[17];
    const float* b_l2down_Y = (const float*)d_in[18];
    const float* w_l2up_Y   = (const float*)d_in[19];
    const float* b_l2up_Y   = (const float*)d_in[20];
    const float* w_c11 = (const float*)d_in[21];
    const float* b_c11 = (const float*)d_in[22];
    const float* w_c12 = (const float*)d_in[23];
    const float* b_c12 = (const float*)d_in[24];
    const float* w_c21 = (const float*)d_in[25];
    const float* b_c21 = (const float*)d_in[26];
    const float* w_c22 = (const float*)d_in[27];
    const float* b_c22 = (const float*)d_in[28];
    const float* pos   = (const float*)d_in[29];
    const float* gamma = (const float*)d_in[30];
    float* out = (float*)d_out;

    ushort* U = (ushort*)d_ws;
    float*  Fp = (float*)d_ws;

    // ---- fresh flat workspace (ush elems; f32 region after 27,598,848 ush; ~98 MB) ----
    const long oXt_h   = 0;
    const long oXt_l   = 3211264;
    const long oDXt_h  = 6422528;
    const long oDXt_l  = 9633792;
    const long oWg1_h  = 12845056;
    const long oWg1_l  = 13893632;
    const long oWval   = 14942208;
    const long oC2_h   = 15466496;
    const long oC2_l   = 15990784;
    const long oW2uT_h = 16515072;
    const long oW2uT_l = 17563648;
    const long oW2dT_h = 18612224;
    const long oW2dT_l = 19660800;
    const long oWvT_h  = 20709376;
    const long oWvT_l  = 21233664;
    const long oW3T_h  = 21757952;
    const long oW3T_l  = 22282240;
    const long oQ_h    = 22806528;
    const long oQ_l    = 23207936;
    const long oKm_h   = 23609344;
    const long oKm_l   = 24010752;
    const long oVT     = 24412160;   // [4][256][416]
    const long oA1_h   = 24838144;
    const long oA1_l   = 24903680;
    const long oA2_h   = 24969216;
    const long oA2_l   = 25493504;
    const long oA3_h   = 26017792;
    const long oA3_l   = 26083328;
    const long oM_h    = 26148864;
    const long oM_l    = 26673152;
    const long oO      = 27197440;   // ends 27598848 ush
    // f32 offsets (float elems)
    const long fPG1   = 13799424;    // [8][1568][512]
    const long fSpart = 20221952;    // [2][16][128][256]
    const long fPG2   = 21270528;    // [8][1568][256]
    const long fbg1   = 24481792;    // 512
    const long fkc    = 24482304;    // 256

    // 1. prep: weight conversions + activation transposes + weight transposes
    prep<<<dim3(11010), 256, 0, stream>>>(
        w_c11, w_c21, w_conv3, w_c22, w_c12, w_value,
        b_c11, b_c21, b_conv3, x, domainX,
        w_l2up, w_l2up_Y, w_l2down, w_l2down_Y, w_value, w_conv3,
        U + oWg1_h, U + oWg1_l, U + oC2_h, U + oC2_l, U + oWval, Fp + fbg1,
        U + oXt_h, U + oXt_l, U + oDXt_h, U + oDXt_l,
        U + oW2uT_h, U + oW2uT_l, U + oW2dT_h, U + oW2dT_l,
        U + oWvT_h, U + oWvT_l, U + oW3T_h, U + oW3T_l);
    // 2. G1: Xt @ [c11|c21|conv3]^T; Q/K 3-pass, V 1-pass; split-K 8
    gmm<EPI_PART, 2><<<dim3(4, 25, 8), 256, 0, stream>>>(
        U + oXt_h, U + oXt_l, 2048, 0, U + oWg1_h, U + oWg1_l, 2048, 0,
        nullptr, 0, 8, 256, Fp + fPG1, nullptr, nullptr, 512, 802816L, TOKENS, 512,
        nullptr, nullptr, nullptr);
    // 3. reduce (8 chunks) -> Q cols 0-127, KmT (c<128), V^T (+pos)
    r_g1<<<dim3(3136), 256, 0, stream>>>(Fp + fPG1, Fp + fbg1, pos,
        U + oQ_h, U + oQ_l, U + oKm_h, U + oKm_l, U + oVT);
    // 4. S1 = [c22|c12] @ W2uT^T  (K=2048, split-K 16)
    gmm<EPI_PART, 1><<<dim3(2, 2, 32), 256, 0, stream>>>(
        U + oC2_h, U + oC2_l, 2048, 262144, U + oW2uT_h, U + oW2uT_l, 2048, 524288,
        nullptr, 0, 16, 128, Fp + fSpart, nullptr, nullptr, 256, 32768L, 128, 256,
        nullptr, nullptr, nullptr);
    r_s<<<dim3(256), 256, 0, stream>>>(Fp + fSpart, U + oA1_h, U + oA1_l,
        nullptr, nullptr, nullptr, nullptr, nullptr, nullptr,
        nullptr, nullptr, nullptr, nullptr, nullptr, nullptr, nullptr, nullptr,
        nullptr, nullptr, nullptr);
    // 5. S2 = A1 @ W2dT^T  (K=256, direct split out)
    gmm<EPI_SPLIT, 1><<<dim3(16, 2, 2), 256, 0, stream>>>(
        U + oA1_h, U + oA1_l, 256, 32768, U + oW2dT_h, U + oW2dT_l, 256, 524288,
        nullptr, 0, 1, 256, nullptr, U + oA2_h, U + oA2_l, 2048, 262144L, 128, 2048,
        nullptr, nullptr, nullptr);
    // 6. S3 = A2 @ WvT^T  (K=2048, split-K 16)
    gmm<EPI_PART, 1><<<dim3(2, 2, 32), 256, 0, stream>>>(
        U + oA2_h, U + oA2_l, 2048, 262144, U + oWvT_h, U + oWvT_l, 2048, 0,
        nullptr, 0, 16, 128, Fp + fSpart, nullptr, nullptr, 256, 32768L, 128, 256,
        nullptr, nullptr, nullptr);
    // 7. r_s(A3) + fused kc constants
    r_s<<<dim3(256), 256, 0, stream>>>(Fp + fSpart, U + oA3_h, U + oA3_l,
        U + oA1_h, U + oA1_l, U + oA2_h, U + oA2_l, w_c22, w_c12,
        b_l1down, b_l1up, b_l2down, b_l2up,
        b_l1down_Y, b_l1up_Y, b_l2down_Y, b_l2up_Y,
        b_c22, b_c12, Fp + fkc);
    // 8. S4 = A3 @ W3T^T -> M = [M_X | M_Q]  (K=256, direct split out)
    gmm<EPI_SPLIT, 1><<<dim3(16, 2, 2), 256, 0, stream>>>(
        U + oA3_h, U + oA3_l, 256, 32768, U + oW3T_h, U + oW3T_l, 256, 0,
        nullptr, 0, 1, 256, nullptr, U + oM_h, U + oM_l, 2048, 262144L, 128, 2048,
        nullptr, nullptr, nullptr);
    // 9. GQK2 = DXt @ M^T  (K=2048, 3-pass, split-K 8)
    gmm<EPI_PART, 1><<<dim3(2, 25, 8), 256, 0, stream>>>(
        U + oDXt_h, U + oDXt_l, 2048, 0, U + oM_h, U + oM_l, 2048, 0,
        nullptr, 0, 8, 256, Fp + fPG2, nullptr, nullptr, 256, 401408L, TOKENS, 256,
        nullptr, nullptr, nullptr);
    // 10. reduce (8 chunks) -> K channels 128+ (KmT scatter), Q cols 128+
    r_qk2<<<dim3(1568), 256, 0, stream>>>(Fp + fPG2, Fp + fkc,
        U + oQ_h, U + oQ_l, U + oKm_h, U + oKm_l);
    // 11. fused attention: logits (3-pass) + softmax + PV -> O bf16
    fattn<<<dim3(7, 4), 256, 0, stream>>>(
        U + oQ_h, U + oQ_l, U + oKm_h, U + oKm_l, U + oVT, U + oO);
    // 12. final: z = O @ w_value^T + b_value ; out = (g*z + x)*z + x
    gmm<EPI_FINAL, 0><<<dim3(16, 25, 1), 256, 0, stream>>>(
        U + oO, nullptr, 256, 0, U + oWval, nullptr, 256, 0,
        b_value, 0, 1, 256, nullptr, nullptr, nullptr, 0, 0L, TOKENS, 2048,
        x, gamma, out);
}

// Round 10
// 170.294 us; speedup vs baseline: 1.3496x; 1.3408x over previous
//
#include <hip/hip_runtime.h>
#include <hip/hip_bf16.h>

// ---------------------------------------------------------------------------
// SCSAttention on MI355X, round 10 = round 9 with fattn restructured to bound
// register pressure (r8/r9 spilled: 26 f32x4 logits/wave > 128-reg budget):
//   block = 16 Q-rows; waves SPLIT the 26 column-frags (logits -> LDS f32);
//   256-thread LDS softmax; waves split PV output channels. 100 blocks.
// Sensitive path (Q/K/logits) = bf16x2 hi/lo 3-pass. 13 launches.
// ---------------------------------------------------------------------------

typedef __attribute__((ext_vector_type(8))) short short8;
typedef __attribute__((ext_vector_type(4))) float f32x4;

#define TOKENS 1568

__device__ __forceinline__ ushort f2bf(float f) {
    uint32_t u = __float_as_uint(f);
    u += 0x7fffu + ((u >> 16) & 1u);   // RNE
    return (ushort)(u >> 16);
}
__device__ __forceinline__ float bf2f(ushort h) { return __uint_as_float(((uint32_t)h) << 16); }
__device__ __forceinline__ void split2(float v, ushort& h, ushort& l) {
    h = f2bf(v); l = f2bf(v - bf2f(h));
}

__device__ __forceinline__ void gl16(const void* g, void* l) {
    __builtin_amdgcn_global_load_lds(
        (const __attribute__((address_space(1))) unsigned int*)g,
        (__attribute__((address_space(3))) unsigned int*)l, 16, 0, 0);
}

#define EPI_PART  0
#define EPI_BF16  1
#define EPI_SPLIT 2
#define EPI_FINAL 3

// C[m][n] = sum_k A[m][k]*W[n][k]; tile 64(M)x128(N), BK=32, 4 waves (2x2),
// wave = 32x64 = 2x4 16x16 frags. SPL: 0 plain, 1 split 3-pass, 2 split iff blockIdx.x<2.
// Double-buffered LDS: STAGE(next) issued before MFMA(cur), one barrier per K-step.
template<int EPI, int SPL>
__global__ __launch_bounds__(256)
void gmm(const ushort* __restrict__ Ah, const ushort* __restrict__ Al, int lda, long sA,
         const ushort* __restrict__ Wh, const ushort* __restrict__ Wl, int ldw, long sW,
         const float* __restrict__ bias, int sB,
         int nkc, int Kc,
         float* __restrict__ fO, ushort* __restrict__ bO, ushort* __restrict__ bO2,
         int ldc, long sC, int M, int N,
         const float* __restrict__ ex, const float* __restrict__ gamma,
         float* __restrict__ fout)
{
    constexpr bool HASL = (SPL >= 1);
    __shared__ __align__(16) ushort sA_h[2][64 * 32];
    __shared__ __align__(16) ushort sW_h[2][128 * 32];
    __shared__ __align__(16) ushort sA_l[HASL ? 2 : 1][HASL ? 64 * 32 : 8];
    __shared__ __align__(16) ushort sW_l[HASL ? 2 : 1][HASL ? 128 * 32 : 8];

    const int tid = threadIdx.x;
    const int bz = blockIdx.z / nkc;
    const int kc = blockIdx.z % nkc;
    const int row0 = blockIdx.y * 64, col0 = blockIdx.x * 128;
    const bool sp = (SPL == 1) || (SPL == 2 && blockIdx.x < 2);

    const int srow = tid >> 2;                       // 0..63
    const int sq   = (tid & 3) ^ (srow & 3);         // swizzled source k-chunk
    int am  = row0 + srow;      if (am  > M - 1) am  = M - 1;
    int wn0 = col0 + srow;      if (wn0 > N - 1) wn0 = N - 1;
    int wn1 = col0 + 64 + srow; if (wn1 > N - 1) wn1 = N - 1;
    const long kbase = (long)kc * Kc + sq * 8;
    const ushort* gA  = Ah + bz * sA + (long)am  * lda + kbase;
    const ushort* gW0 = Wh + bz * sW + (long)wn0 * ldw + kbase;
    const ushort* gW1 = Wh + bz * sW + (long)wn1 * ldw + kbase;
    const ushort *gAl = nullptr, *gWl0 = nullptr, *gWl1 = nullptr;
    if constexpr (HASL) {
        if (sp) {
            gAl  = Al + bz * sA + (long)am  * lda + kbase;
            gWl0 = Wl + bz * sW + (long)wn0 * ldw + kbase;
            gWl1 = Wl + bz * sW + (long)wn1 * ldw + kbase;
        }
    }
    const int wb = (tid & 192) * 8;                  // wave-uniform LDS chunk base

    auto STAGE = [&](int buf, int k0) {
        gl16(gA + k0, &sA_h[buf][wb]);
        gl16(gW0 + k0, &sW_h[buf][wb]);
        gl16(gW1 + k0, &sW_h[buf][2048 + wb]);
        if constexpr (HASL) {
            if (sp) {
                gl16(gAl + k0, &sA_l[buf][wb]);
                gl16(gWl0 + k0, &sW_l[buf][wb]);
                gl16(gWl1 + k0, &sW_l[buf][2048 + wb]);
            }
        }
    };

    const int lane = tid & 63, wv = tid >> 6;
    const int wr = (wv >> 1) * 32, wc = (wv & 1) * 64;
    const int fr = lane & 15;
    const int ksw = ((lane >> 4) ^ (lane & 3)) * 8;
    int aoff[2], boff[4];
#pragma unroll
    for (int mi = 0; mi < 2; ++mi) aoff[mi] = (wr + mi * 16 + fr) * 32 + ksw;
#pragma unroll
    for (int ni = 0; ni < 4; ++ni) boff[ni] = (wc + ni * 16 + fr) * 32 + ksw;

    f32x4 acc[2][4];
#pragma unroll
    for (int mi = 0; mi < 2; ++mi)
#pragma unroll
        for (int ni = 0; ni < 4; ++ni) acc[mi][ni] = (f32x4){0.f, 0.f, 0.f, 0.f};

    STAGE(0, 0);
    __syncthreads();
    int cur = 0;
    for (int k0 = 0; k0 < Kc; k0 += 32) {
        if (k0 + 32 < Kc) STAGE(cur ^ 1, k0 + 32);   // prefetch next K-tile

        short8 fa[2], fb[4];
#pragma unroll
        for (int mi = 0; mi < 2; ++mi) fa[mi] = *(const short8*)&sA_h[cur][aoff[mi]];
#pragma unroll
        for (int ni = 0; ni < 4; ++ni) fb[ni] = *(const short8*)&sW_h[cur][boff[ni]];
#pragma unroll
        for (int mi = 0; mi < 2; ++mi)
#pragma unroll
            for (int ni = 0; ni < 4; ++ni)
                acc[mi][ni] = __builtin_amdgcn_mfma_f32_16x16x32_bf16(fa[mi], fb[ni], acc[mi][ni], 0, 0, 0);
        if constexpr (HASL) {
            if (sp) {
                short8 ga[2], gb[4];
#pragma unroll
                for (int mi = 0; mi < 2; ++mi) ga[mi] = *(const short8*)&sA_l[cur][aoff[mi]];
#pragma unroll
                for (int ni = 0; ni < 4; ++ni) gb[ni] = *(const short8*)&sW_l[cur][boff[ni]];
#pragma unroll
                for (int mi = 0; mi < 2; ++mi)
#pragma unroll
                    for (int ni = 0; ni < 4; ++ni) {
                        acc[mi][ni] = __builtin_amdgcn_mfma_f32_16x16x32_bf16(fa[mi], gb[ni], acc[mi][ni], 0, 0, 0);
                        acc[mi][ni] = __builtin_amdgcn_mfma_f32_16x16x32_bf16(ga[mi], fb[ni], acc[mi][ni], 0, 0, 0);
                    }
            }
        }
        __syncthreads();
        cur ^= 1;
    }

    const int q4 = (lane >> 4) * 4;
    float g = 0.f;
    if constexpr (EPI == EPI_FINAL) g = gamma[0];
#pragma unroll
    for (int mi = 0; mi < 2; ++mi)
#pragma unroll
        for (int ni = 0; ni < 4; ++ni)
#pragma unroll
            for (int qi = 0; qi < 4; ++qi) {
                int m = row0 + wr + mi * 16 + q4 + qi;
                int n = col0 + wc + ni * 16 + fr;
                if (m >= M || n >= N) continue;
                float v = acc[mi][ni][qi];
                if (bias) v += bias[bz * sB + n];
                if constexpr (EPI == EPI_PART) {
                    fO[(long)blockIdx.z * sC + (long)m * ldc + n] = v;
                } else if constexpr (EPI == EPI_BF16) {
                    bO[(long)blockIdx.z * sC + (long)m * ldc + n] = f2bf(v);
                } else if constexpr (EPI == EPI_SPLIT) {
                    long o = (long)blockIdx.z * sC + (long)m * ldc + n;
                    ushort h, l; split2(v, h, l);
                    bO[o] = h; bO2[o] = l;
                } else {
                    int nimg = m / 49, p = m % 49;
                    long xi = (long)nimg * (2048 * 49) + (long)n * 49 + p;
                    float xv = ex[xi];
                    fout[xi] = (g * v + xv) * v + xv;
                }
            }
}

// prep: [0,8194) wconv ; [8194,10242) tx_split ; [10242,11010) wtrans.
__global__ __launch_bounds__(256)
void prep(const float* c11, const float* c21, const float* conv3,
          const float* c22, const float* c12, const float* wval,
          const float* b_c11, const float* b_c21, const float* b_conv3,
          const float* x, const float* dX,
          const float* w2u, const float* w2uY, const float* w2d, const float* w2dY,
          const float* wv, const float* w3,
          ushort* Wg1h, ushort* Wg1l, ushort* C2h, ushort* C2l, ushort* Wvalb,
          float* bg1,
          ushort* Xth, ushort* Xtl, ushort* DXth, ushort* DXtl,
          ushort* W2uTh, ushort* W2uTl, ushort* W2dTh, ushort* W2dTl,
          ushort* WvTh, ushort* WvTl, ushort* W3Th, ushort* W3Tl)
{
    __shared__ float tile[64][65];
    int b = blockIdx.x;
    int tid = threadIdx.x;
    if (b < 8194) {
        int e = b * 256 + tid;
        if (e < 1048576) {
            float v = e < 262144 ? c11[e] : e < 524288 ? c21[e - 262144] : conv3[e - 524288];
            ushort h, l; split2(v, h, l); Wg1h[e] = h; Wg1l[e] = l;
        } else if (e < 1572864) {
            int i = e - 1048576;
            float v = i < 262144 ? c22[i] : c12[i - 262144];
            ushort h, l; split2(v, h, l); C2h[i] = h; C2l[i] = l;
        } else if (e < 2097152) {
            int i = e - 1572864; Wvalb[i] = f2bf(wval[i]);
        } else if (e < 2097664) {
            int i = e - 2097152;
            bg1[i] = i < 128 ? b_c11[i] : i < 256 ? b_c21[i - 128] : b_conv3[i - 256];
        }
    } else if (b < 10242) {
        int local = b - 8194;                 // 0..2047
        int z = local >> 10;
        int rem = local & 1023;
        int n = rem & 31, c0 = (rem >> 5) * 64;
        const float* src = z ? dX : x;
        ushort* oh = z ? DXth : Xth;
        ushort* ol = z ? DXtl : Xtl;
        const float* s = src + (long)n * (2048 * 49) + (long)c0 * 49;
        for (int idx = tid; idx < 64 * 49; idx += 256)
            tile[idx / 49][idx % 49] = s[idx];
        __syncthreads();
        for (int idx = tid; idx < 49 * 64; idx += 256) {
            int p = idx >> 6, cl = idx & 63;
            float v = tile[cl][p];
            long o = (long)(n * 49 + p) * 2048 + c0 + cl;
            ushort h, l; split2(v, h, l);
            oh[o] = h; ol[o] = l;
        }
    } else {
        int local = b - 10242;                // 0..767
        int z = local >> 7, t = local & 127;
        const float* src; ushort *dh, *dl; int rows;
        switch (z) {
            case 0:  src = w2u;  dh = W2uTh;          dl = W2uTl;          rows = 2048; break;
            case 1:  src = w2uY; dh = W2uTh + 524288; dl = W2uTl + 524288; rows = 2048; break;
            case 2:  src = w2d;  dh = W2dTh;          dl = W2dTl;          rows = 256;  break;
            case 3:  src = w2dY; dh = W2dTh + 524288; dl = W2dTl + 524288; rows = 256;  break;
            case 4:  src = wv;   dh = WvTh;           dl = WvTl;           rows = 2048; break;
            default: src = w3;   dh = W3Th;           dl = W3Tl;           rows = 256;  break;
        }
        int cols = 524288 / rows;
        int tilesX = cols >> 6;
        int tx = t % tilesX, ty = t / tilesX;
        for (int i = tid; i < 4096; i += 256) {
            int r = i >> 6, c = i & 63;
            tile[r][c] = src[(long)(ty * 64 + r) * cols + tx * 64 + c];
        }
        __syncthreads();
        for (int i = tid; i < 4096; i += 256) {
            int c = i >> 6, r = i & 63;
            float v = tile[r][c];
            ushort h, l; split2(v, h, l);
            long o = (long)(tx * 64 + c) * rows + ty * 64 + r;
            dh[o] = h; dl[o] = l;
        }
    }
}

// G1 reduce (8 K-chunks): n<128 -> Q cols 0-127 split; n<256 -> K scatter into KmT;
// n>=256 -> V (+pos) transposed [b][c][416], pad-zeroed.
__global__ __launch_bounds__(256)
void r_g1(const float* __restrict__ P, const float* __restrict__ bg1,
          const float* __restrict__ pos,
          ushort* Qh, ushort* Ql, ushort* KmH, ushort* KmL, ushort* Vh)
{
    int idx = blockIdx.x * 256 + threadIdx.x;      // 1568*512
    int m = idx >> 9, n = idx & 511;
    float v = bg1[n];
#pragma unroll
    for (int k = 0; k < 8; ++k) v += P[(long)k * 802816 + idx];
    int p = m % 49, img = m / 49;
    int f = img & 7, b = img >> 3;
    if (n < 128) {
        ushort h, l; split2(v, h, l);
        Qh[m * 256 + n] = h; Ql[m * 256 + n] = l;
    } else if (n < 256) {
        int c = n - 128;
        int flat = (p / 7) * 14336 + f * 1792 + (p % 7) * 256 + c;
        int ci = flat / 392, mm = flat % 392;
        long o = (long)b * 100352 + (long)mm * 256 + ci;
        ushort h, l; split2(v, h, l);
        KmH[o] = h; KmL[o] = l;
    } else {
        int c = n - 256;
        v += pos[f * 12544 + c * 49 + p];
        int s = m % 392;
        long o = (long)b * 106496 + (long)c * 416 + s;
        Vh[o] = f2bf(v);
        if (s < 24) Vh[o + 392] = 0;               // zero K-pad columns
    }
}

// GQK2 reduce (8 K-chunks + folded consts): j<128 -> K channel 128+j scatter into KmT;
// j>=128 -> Q col j.
__global__ __launch_bounds__(256)
void r_qk2(const float* __restrict__ P, const float* __restrict__ kc,
           ushort* Qh, ushort* Ql, ushort* KmH, ushort* KmL)
{
    int idx = blockIdx.x * 256 + threadIdx.x;      // 1568*256
    int m = idx >> 8, j = idx & 255;
    float v = kc[j];
#pragma unroll
    for (int k = 0; k < 8; ++k) v += P[(long)k * 401408 + idx];
    ushort h, l; split2(v, h, l);
    if (j < 128) {
        int c = 128 + j;
        int p = m % 49, img = m / 49, f = img & 7, b = img >> 3;
        int flat = (p / 7) * 14336 + f * 1792 + (p % 7) * 256 + c;
        int ci = flat / 392, mm = flat % 392;
        long o = (long)b * 100352 + (long)mm * 256 + ci;
        KmH[o] = h; KmL[o] = l;
    } else {
        Qh[m * 256 + j] = h; Ql[m * 256 + j] = l;
    }
}

// Weight-chain split-K reduce: [2][16][128][256] -> split hi/lo [2][128][256].
// If kc != nullptr (A3 call): additionally fold the bias constants
//   kc_z[i] = A3_z[i]·b1d + A2_z[i]·b1u + A1_z[i]·b2d + C2_z[i]·b2u + bc_z[i]
__global__ __launch_bounds__(256)
void r_s(const float* __restrict__ P, ushort* __restrict__ Oh, ushort* __restrict__ Ol,
         const ushort* __restrict__ A1h, const ushort* __restrict__ A1l,
         const ushort* __restrict__ A2h, const ushort* __restrict__ A2l,
         const float* __restrict__ c22, const float* __restrict__ c12,
         const float* __restrict__ b1dX, const float* __restrict__ b1uX,
         const float* __restrict__ b2dX, const float* __restrict__ b2uX,
         const float* __restrict__ b1dY, const float* __restrict__ b1uY,
         const float* __restrict__ b2dY, const float* __restrict__ b2uY,
         const float* __restrict__ bc22, const float* __restrict__ bc12,
         float* __restrict__ kc)
{
    int tid = threadIdx.x;
    int blk = blockIdx.x;                          // = z*128 + i
    int idx = blk * 256 + tid;
    int br = idx >> 15, e = idx & 32767;
    const float* p = P + (long)br * 524288;
    float v = 0.f;
#pragma unroll
    for (int k = 0; k < 16; ++k) v += p[k * 32768 + e];
    ushort h, l; split2(v, h, l);
    Oh[idx] = h; Ol[idx] = l;

    if (kc) {
        int z = blk >> 7, i = blk & 127;
        const float* b1d = z ? b1dY : b1dX;
        const float* b1u = z ? b1uY : b1uX;
        const float* b2d = z ? b2dY : b2dX;
        const float* b2u = z ? b2uY : b2uX;
        const float* cw  = (z ? c12 : c22) + (long)i * 2048;
        const ushort* a1h = A1h + (long)blk * 256;
        const ushort* a1l = A1l + (long)blk * 256;
        const ushort* a2h = A2h + (long)blk * 2048;
        const ushort* a2l = A2l + (long)blk * 2048;
        float acc = v * b1d[tid];                                    // A3 term (c = tid)
        acc = fmaf(bf2f(a1h[tid]) + bf2f(a1l[tid]), b2d[tid], acc);  // A1 term
#pragma unroll
        for (int u = 0; u < 8; ++u) {
            int c = u * 256 + tid;
            acc = fmaf(bf2f(a2h[c]) + bf2f(a2l[c]), b1u[c], acc);
            acc = fmaf(cw[c], b2u[c], acc);
        }
        __shared__ float red[4];
        for (int off = 32; off; off >>= 1) acc += __shfl_down(acc, off, 64);
        if ((tid & 63) == 0) red[tid >> 6] = acc;
        __syncthreads();
        if (tid == 0)
            kc[blk] = red[0] + red[1] + red[2] + red[3] + (z ? bc12 : bc22)[i];
    }
}

// Fused attention v3, register-bounded: block = 16 Q-rows x one batch, 4 waves.
// Phase 1: waves split the 26 column-frags; 3-pass QK^T; raw f32 logits -> LDS.
// Phase 2: 256-thread LDS softmax (16 threads/row, shfl_xor(16) reduce) -> bf16 P.
// Phase 3: waves split 16 output-channel frags (4 each); PV from LDS P + global V.
__global__ __launch_bounds__(256)
void fattn(const ushort* __restrict__ Qh, const ushort* __restrict__ Ql,
           const ushort* __restrict__ Kmh, const ushort* __restrict__ Kml,
           const ushort* __restrict__ VT, ushort* __restrict__ O)
{
    __shared__ float raw[16 * 420];
    __shared__ ushort P[16 * 424];
    const int b = blockIdx.y;
    const int r0 = blockIdx.x * 16;
    const int tid = threadIdx.x;
    const int lane = tid & 63, wv = tid >> 6;
    const int fr = lane & 15, g = lane >> 4;
    const int kb = g * 8;
    const long base = (long)b * 100352;
    const long vbase = (long)b * 106496;

    // Q fragments for rows r0..r0+15 (A-frag row = fr), K=256 -> 8 chunks
    int qr = r0 + fr; if (qr > 391) qr = 391;
    const ushort* qph = Qh + base + (long)qr * 256 + kb;
    const ushort* qpl = Ql + base + (long)qr * 256 + kb;
    short8 qh[8], ql[8];
#pragma unroll
    for (int kf = 0; kf < 8; ++kf) {
        qh[kf] = *(const short8*)(qph + kf * 32);
        ql[kf] = *(const short8*)(qpl + kf * 32);
    }

    // Phase 1: wave wv handles nf = wv, wv+4, ... (26 col-frags of 16)
    for (int nf = wv; nf < 26; nf += 4) {
        int kcol = nf * 16 + fr; if (kcol > 391) kcol = 391;
        const ushort* kph = Kmh + base + (long)kcol * 256 + kb;
        const ushort* kpl = Kml + base + (long)kcol * 256 + kb;
        f32x4 a = (f32x4){0.f, 0.f, 0.f, 0.f};
#pragma unroll
        for (int kf = 0; kf < 8; ++kf) {
            short8 bh = *(const short8*)(kph + kf * 32);
            short8 bl = *(const short8*)(kpl + kf * 32);
            a = __builtin_amdgcn_mfma_f32_16x16x32_bf16(qh[kf], bh, a, 0, 0, 0);
            a = __builtin_amdgcn_mfma_f32_16x16x32_bf16(qh[kf], bl, a, 0, 0, 0);
            a = __builtin_amdgcn_mfma_f32_16x16x32_bf16(ql[kf], bh, a, 0, 0, 0);
        }
#pragma unroll
        for (int q = 0; q < 4; ++q)
            raw[(g * 4 + q) * 420 + nf * 16 + fr] = a[q];
    }
    __syncthreads();

    // Phase 2: softmax. thread (row = tid>>4, j = tid&15) scans cols j+16k.
    {
        int row = tid >> 4, j = tid & 15;
        float v[26];
        float m = -1e30f;
#pragma unroll
        for (int k = 0; k < 26; ++k) {
            int col = j + 16 * k;
            v[k] = (col < 392) ? raw[row * 420 + col] : -1e30f;
            m = fmaxf(m, v[k]);
        }
#pragma unroll
        for (int off = 8; off; off >>= 1) m = fmaxf(m, __shfl_xor(m, off, 16));
        float s = 0.f;
#pragma unroll
        for (int k = 0; k < 26; ++k) { v[k] = __expf(v[k] - m); s += v[k]; }
#pragma unroll
        for (int off = 8; off; off >>= 1) s += __shfl_xor(s, off, 16);
        float inv = 1.f / s;
#pragma unroll
        for (int k = 0; k < 26; ++k) {
            int col = j + 16 * k;
            P[row * 424 + col] = (col < 392) ? f2bf(v[k] * inv) : (ushort)0;
        }
    }
    __syncthreads();

    // Phase 3: PV. wave wv computes output channel frags cf0..cf0+3.
    const int cf0 = wv * 4;
    f32x4 o[4];
#pragma unroll
    for (int c = 0; c < 4; ++c) o[c] = (f32x4){0.f, 0.f, 0.f, 0.f};
#pragma unroll
    for (int kf = 0; kf < 13; ++kf) {
        short8 pa = *(const short8*)&P[fr * 424 + kf * 32 + kb];
#pragma unroll
        for (int c = 0; c < 4; ++c) {
            const ushort* vp = VT + vbase + (long)((cf0 + c) * 16 + fr) * 416 + kf * 32 + kb;
            short8 vb = *(const short8*)vp;
            o[c] = __builtin_amdgcn_mfma_f32_16x16x32_bf16(pa, vb, o[c], 0, 0, 0);
        }
    }
#pragma unroll
    for (int c = 0; c < 4; ++c)
#pragma unroll
        for (int q = 0; q < 4; ++q) {
            int orow = r0 + g * 4 + q;
            if (orow < 392)
                O[base + (long)orow * 256 + (cf0 + c) * 16 + fr] = f2bf(o[c][q]);
        }
}

extern "C" void kernel_launch(void* const* d_in, const int* in_sizes, int n_in,
                              void* d_out, int out_size, void* d_ws, size_t ws_size,
                              hipStream_t stream)
{
    const float* x        = (const float*)d_in[0];
    const float* domainX  = (const float*)d_in[1];
    const float* w_conv3  = (const float*)d_in[5];
    const float* b_conv3  = (const float*)d_in[6];
    const float* w_value  = (const float*)d_in[7];
    const float* b_value  = (const float*)d_in[8];
    const float* b_l1down   = (const float*)d_in[9];
    const float* b_l1up     = (const float*)d_in[10];
    const float* b_l1down_Y = (const float*)d_in[11];
    const float* b_l1up_Y   = (const float*)d_in[12];
    const float* w_l2down   = (const float*)d_in[13];
    const float* b_l2down   = (const float*)d_in[14];
    const float* w_l2up     = (const float*)d_in[15];
    const float* b_l2up     = (const float*)d_in[16];
    const float* w_l2down_Y = (const float*)d_in[17];
    const float* b_l2down_Y = (const float*)d_in[18];
    const float* w_l2up_Y   = (const float*)d_in[19];
    const float* b_l2up_Y   = (const float*)d_in[20];
    const float* w_c11 = (const float*)d_in[21];
    const float* b_c11 = (const float*)d_in[22];
    const float* w_c12 = (const float*)d_in[23];
    const float* b_c12 = (const float*)d_in[24];
    const float* w_c21 = (const float*)d_in[25];
    const float* b_c21 = (const float*)d_in[26];
    const float* w_c22 = (const float*)d_in[27];
    const float* b_c22 = (const float*)d_in[28];
    const float* pos   = (const float*)d_in[29];
    const float* gamma = (const float*)d_in[30];
    float* out = (float*)d_out;

    ushort* U = (ushort*)d_ws;
    float*  Fp = (float*)d_ws;

    // ---- fresh flat workspace (ush elems; f32 region after 27,598,848 ush; ~98 MB) ----
    const long oXt_h   = 0;
    const long oXt_l   = 3211264;
    const long oDXt_h  = 6422528;
    const long oDXt_l  = 9633792;
    const long oWg1_h  = 12845056;
    const long oWg1_l  = 13893632;
    const long oWval   = 14942208;
    const long oC2_h   = 15466496;
    const long oC2_l   = 15990784;
    const long oW2uT_h = 16515072;
    const long oW2uT_l = 17563648;
    const long oW2dT_h = 18612224;
    const long oW2dT_l = 19660800;
    const long oWvT_h  = 20709376;
    const long oWvT_l  = 21233664;
    const long oW3T_h  = 21757952;
    const long oW3T_l  = 22282240;
    const long oQ_h    = 22806528;
    const long oQ_l    = 23207936;
    const long oKm_h   = 23609344;
    const long oKm_l   = 24010752;
    const long oVT     = 24412160;   // [4][256][416]
    const long oA1_h   = 24838144;
    const long oA1_l   = 24903680;
    const long oA2_h   = 24969216;
    const long oA2_l   = 25493504;
    const long oA3_h   = 26017792;
    const long oA3_l   = 26083328;
    const long oM_h    = 26148864;
    const long oM_l    = 26673152;
    const long oO      = 27197440;   // ends 27598848 ush
    // f32 offsets (float elems)
    const long fPG1   = 13799424;    // [8][1568][512]
    const long fSpart = 20221952;    // [2][16][128][256]
    const long fPG2   = 21270528;    // [8][1568][256]
    const long fbg1   = 24481792;    // 512
    const long fkc    = 24482304;    // 256

    // 1. prep: weight conversions + activation transposes + weight transposes
    prep<<<dim3(11010), 256, 0, stream>>>(
        w_c11, w_c21, w_conv3, w_c22, w_c12, w_value,
        b_c11, b_c21, b_conv3, x, domainX,
        w_l2up, w_l2up_Y, w_l2down, w_l2down_Y, w_value, w_conv3,
        U + oWg1_h, U + oWg1_l, U + oC2_h, U + oC2_l, U + oWval, Fp + fbg1,
        U + oXt_h, U + oXt_l, U + oDXt_h, U + oDXt_l,
        U + oW2uT_h, U + oW2uT_l, U + oW2dT_h, U + oW2dT_l,
        U + oWvT_h, U + oWvT_l, U + oW3T_h, U + oW3T_l);
    // 2. G1: Xt @ [c11|c21|conv3]^T; Q/K 3-pass, V 1-pass; split-K 8
    gmm<EPI_PART, 2><<<dim3(4, 25, 8), 256, 0, stream>>>(
        U + oXt_h, U + oXt_l, 2048, 0, U + oWg1_h, U + oWg1_l, 2048, 0,
        nullptr, 0, 8, 256, Fp + fPG1, nullptr, nullptr, 512, 802816L, TOKENS, 512,
        nullptr, nullptr, nullptr);
    // 3. reduce (8 chunks) -> Q cols 0-127, KmT (c<128), V^T (+pos)
    r_g1<<<dim3(3136), 256, 0, stream>>>(Fp + fPG1, Fp + fbg1, pos,
        U + oQ_h, U + oQ_l, U + oKm_h, U + oKm_l, U + oVT);
    // 4. S1 = [c22|c12] @ W2uT^T  (K=2048, split-K 16)
    gmm<EPI_PART, 1><<<dim3(2, 2, 32), 256, 0, stream>>>(
        U + oC2_h, U + oC2_l, 2048, 262144, U + oW2uT_h, U + oW2uT_l, 2048, 524288,
        nullptr, 0, 16, 128, Fp + fSpart, nullptr, nullptr, 256, 32768L, 128, 256,
        nullptr, nullptr, nullptr);
    r_s<<<dim3(256), 256, 0, stream>>>(Fp + fSpart, U + oA1_h, U + oA1_l,
        nullptr, nullptr, nullptr, nullptr, nullptr, nullptr,
        nullptr, nullptr, nullptr, nullptr, nullptr, nullptr, nullptr, nullptr,
        nullptr, nullptr, nullptr);
    // 5. S2 = A1 @ W2dT^T  (K=256, direct split out)
    gmm<EPI_SPLIT, 1><<<dim3(16, 2, 2), 256, 0, stream>>>(
        U + oA1_h, U + oA1_l, 256, 32768, U + oW2dT_h, U + oW2dT_l, 256, 524288,
        nullptr, 0, 1, 256, nullptr, U + oA2_h, U + oA2_l, 2048, 262144L, 128, 2048,
        nullptr, nullptr, nullptr);
    // 6. S3 = A2 @ WvT^T  (K=2048, split-K 16)
    gmm<EPI_PART, 1><<<dim3(2, 2, 32), 256, 0, stream>>>(
        U + oA2_h, U + oA2_l, 2048, 262144, U + oWvT_h, U + oWvT_l, 2048, 0,
        nullptr, 0, 16, 128, Fp + fSpart, nullptr, nullptr, 256, 32768L, 128, 256,
        nullptr, nullptr, nullptr);
    // 7. r_s(A3) + fused kc constants
    r_s<<<dim3(256), 256, 0, stream>>>(Fp + fSpart, U + oA3_h, U + oA3_l,
        U + oA1_h, U + oA1_l, U + oA2_h, U + oA2_l, w_c22, w_c12,
        b_l1down, b_l1up, b_l2down, b_l2up,
        b_l1down_Y, b_l1up_Y, b_l2down_Y, b_l2up_Y,
        b_c22, b_c12, Fp + fkc);
    // 8. S4 = A3 @ W3T^T -> M = [M_X | M_Q]  (K=256, direct split out)
    gmm<EPI_SPLIT, 1><<<dim3(16, 2, 2), 256, 0, stream>>>(
        U + oA3_h, U + oA3_l, 256, 32768, U + oW3T_h, U + oW3T_l, 256, 0,
        nullptr, 0, 1, 256, nullptr, U + oM_h, U + oM_l, 2048, 262144L, 128, 2048,
        nullptr, nullptr, nullptr);
    // 9. GQK2 = DXt @ M^T  (K=2048, 3-pass, split-K 8)
    gmm<EPI_PART, 1><<<dim3(2, 25, 8), 256, 0, stream>>>(
        U + oDXt_h, U + oDXt_l, 2048, 0, U + oM_h, U + oM_l, 2048, 0,
        nullptr, 0, 8, 256, Fp + fPG2, nullptr, nullptr, 256, 401408L, TOKENS, 256,
        nullptr, nullptr, nullptr);
    // 10. reduce (8 chunks) -> K channels 128+ (KmT scatter), Q cols 128+
    r_qk2<<<dim3(1568), 256, 0, stream>>>(Fp + fPG2, Fp + fkc,
        U + oQ_h, U + oQ_l, U + oKm_h, U + oKm_l);
    // 11. fused attention v3 (16-row blocks, 100 blocks)
    fattn<<<dim3(25, 4), 256, 0, stream>>>(
        U + oQ_h, U + oQ_l, U + oKm_h, U + oKm_l, U + oVT, U + oO);
    // 12. final: z = O @ w_value^T + b_value ; out = (g*z + x)*z + x
    gmm<EPI_FINAL, 0><<<dim3(16, 25, 1), 256, 0, stream>>>(
        U + oO, nullptr, 256, 0, U + oWval, nullptr, 256, 0,
        b_value, 0, 1, 256, nullptr, nullptr, nullptr, 0, 0L, TOKENS, 2048,
        x, gamma, out);
}